// Round 11
// baseline (41.101 us; speedup 1.0000x reference)
//
#include <hip/hip_runtime.h>
#include <hip/hip_bf16.h>
#include <math.h>

typedef unsigned short u16;
typedef unsigned int u32;
typedef __attribute__((ext_vector_type(8))) short bf16x8;
typedef __attribute__((ext_vector_type(4))) float f32x4;

#define NB 128
#define ND 1024
#define NO 512
#define EPSV 1e-5f
#define SCALEQK 0.04419417382415922f   // 1/sqrt(512)
#define LOG2E 1.4426950408889634f

static __device__ __forceinline__ float fast_exp2(float v) {
#if __has_builtin(__builtin_amdgcn_exp2f)
  return __builtin_amdgcn_exp2f(v);
#else
  return exp2f(v);
#endif
}
static __device__ __forceinline__ float fast_rcp(float v) {
#if __has_builtin(__builtin_amdgcn_rcpf)
  return __builtin_amdgcn_rcpf(v);
#else
  return 1.f / v;
#endif
}
static __device__ __forceinline__ u16 bf16_rtn(float f) {
  unsigned u = __float_as_uint(f);
  return (u16)((u + 0x7FFFu + ((u >> 16) & 1u)) >> 16);
}
static __device__ __forceinline__ void bf16_split(float f, u16& h, u16& l) {
  h = bf16_rtn(f);
  l = bf16_rtn(f - __uint_as_float(((unsigned)h) << 16));
}
static __device__ __forceinline__ float asinh_fast(float x) {
  const float ax = fabsf(x);
  const float s = sqrtf(fmaf(ax, ax, 1.f));
  return copysignf(__logf(ax + s), x);
}
static __device__ __forceinline__ float tanh_fast(float x) {
  return 1.f - 2.f * fast_rcp(fast_exp2(x * (2.f * LOG2E)) + 1.f);
}
static __device__ __forceinline__ float sig_fast(float x) {
  return fast_rcp(1.f + fast_exp2(-x * LOG2E));
}
static __device__ __forceinline__ float sinh_fast(float x) {
  const float z = fast_exp2(x * LOG2E);
  return 0.5f * (z - fast_rcp(z));
}

// =============== gemmA tile: 128 rows x 64 cols, K-span 128 (2 chunks of 64) ===============
// A staged inline from fp32 x (AMODE 2: asinh first). B: WMODE 0 plain, 1 tanh(W0)*sig(W1).
template <int AMODE, int WMODE>
static __device__ __forceinline__ void gemmA_tile(
    const float* __restrict__ Xf, const float* __restrict__ W0,
    const float* __restrict__ W1, float* __restrict__ outp,
    int o0, int k0, char* smem) {
  u16* AshH = (u16*)smem;                // [128][64] swizzled, 16 KB
  u16* AshL = (u16*)(smem + 16384);
  u16* BshH = (u16*)(smem + 32768);      // [64 col][64 k] swizzled, 8 KB
  u16* BshL = (u16*)(smem + 40960);
  const int t = threadIdx.x;
  const int lane = t & 63;
  const int wr = (t >> 6) & 3;
  const int wc = t >> 8;
  const f32x4 vz = {0.f, 0.f, 0.f, 0.f};
  f32x4 acc[2][2];
  acc[0][0] = vz; acc[0][1] = vz; acc[1][0] = vz; acc[1][1] = vz;

#pragma unroll
  for (int c = 0; c < 2; ++c) {
    const int kc = k0 + c * 64;
    if (c) __syncthreads();
    // ---- stage A: fp32 x, inline bf16 split (+ asinh for AMODE 2) ----
    {
      const int rowb = t >> 4;
      const int e0 = (t & 15) * 4;
#pragma unroll
      for (int pass = 0; pass < 4; ++pass) {
        const int row = pass * 32 + rowb;
        const float4 v = *(const float4*)(Xf + (size_t)row * ND + kc + e0);
        float e[4] = {v.x, v.y, v.z, v.w};
        if (AMODE == 2) {
#pragma unroll
          for (int i = 0; i < 4; ++i) e[i] = asinh_fast(e[i]);
        }
        u16 h[4], l[4];
#pragma unroll
        for (int i = 0; i < 4; ++i) bf16_split(e[i], h[i], l[i]);
        const int byte = (row * 128 + e0 * 2) ^ ((row & 7) << 4);
        *(uint2*)((char*)AshH + byte) =
            make_uint2((u32)h[0] | ((u32)h[1] << 16), (u32)h[2] | ((u32)h[3] << 16));
        *(uint2*)((char*)AshL + byte) =
            make_uint2((u32)l[0] | ((u32)l[1] << 16), (u32)l[2] | ((u32)l[3] << 16));
      }
    }
    // ---- stage B transposed [col][k] ----
    {
      const int kp = t >> 4, og = t & 15;
      const int gk = kc + kp * 2, go = o0 + og * 4;
      float4 w0 = *(const float4*)&W0[(size_t)gk * NO + go];
      float4 w1 = *(const float4*)&W0[(size_t)(gk + 1) * NO + go];
      if (WMODE) {
        const float4 m0 = *(const float4*)&W1[(size_t)gk * NO + go];
        const float4 m1 = *(const float4*)&W1[(size_t)(gk + 1) * NO + go];
        w0.x = tanh_fast(w0.x) * sig_fast(m0.x);
        w0.y = tanh_fast(w0.y) * sig_fast(m0.y);
        w0.z = tanh_fast(w0.z) * sig_fast(m0.z);
        w0.w = tanh_fast(w0.w) * sig_fast(m0.w);
        w1.x = tanh_fast(w1.x) * sig_fast(m1.x);
        w1.y = tanh_fast(w1.y) * sig_fast(m1.y);
        w1.z = tanh_fast(w1.z) * sig_fast(m1.z);
        w1.w = tanh_fast(w1.w) * sig_fast(m1.w);
      }
      const float e0v[4] = {w0.x, w0.y, w0.z, w0.w};
      const float e1v[4] = {w1.x, w1.y, w1.z, w1.w};
#pragma unroll
      for (int j = 0; j < 4; ++j) {
        u16 h0, l0, h1, l1;
        bf16_split(e0v[j], h0, l0);
        bf16_split(e1v[j], h1, l1);
        const int col = og * 4 + j;
        const int byte = (col * 128 + kp * 4) ^ ((col & 7) << 4);
        *(u32*)((char*)BshH + byte) = (u32)h0 | ((u32)h1 << 16);
        *(u32*)((char*)BshL + byte) = (u32)l0 | ((u32)l1 << 16);
      }
    }
    __syncthreads();
    // ---- compute: 2 k-steps of 32, bf16 h/l 3-pass ----
#pragma unroll
    for (int ks2 = 0; ks2 < 2; ++ks2) {
      const int kb = ((lane >> 4) * 16) + ks2 * 64;
      bf16x8 a_h[2], a_l[2], b_h[2], b_l[2];
#pragma unroll
      for (int m = 0; m < 2; ++m) {
        const int row = wr * 32 + m * 16 + (lane & 15);
        const int byte = (row * 128 + kb) ^ ((row & 7) << 4);
        a_h[m] = *(const bf16x8*)((const char*)AshH + byte);
        a_l[m] = *(const bf16x8*)((const char*)AshL + byte);
      }
#pragma unroll
      for (int n = 0; n < 2; ++n) {
        const int col = wc * 32 + n * 16 + (lane & 15);
        const int byte = (col * 128 + kb) ^ ((col & 7) << 4);
        b_h[n] = *(const bf16x8*)((const char*)BshH + byte);
        b_l[n] = *(const bf16x8*)((const char*)BshL + byte);
      }
#pragma unroll
      for (int m = 0; m < 2; ++m)
#pragma unroll
        for (int n = 0; n < 2; ++n) {
          acc[m][n] = __builtin_amdgcn_mfma_f32_16x16x32_bf16(a_h[m], b_h[n], acc[m][n], 0, 0, 0);
          acc[m][n] = __builtin_amdgcn_mfma_f32_16x16x32_bf16(a_h[m], b_l[n], acc[m][n], 0, 0, 0);
          acc[m][n] = __builtin_amdgcn_mfma_f32_16x16x32_bf16(a_l[m], b_h[n], acc[m][n], 0, 0, 0);
        }
    }
  }
  // ---- epilogue ----
#pragma unroll
  for (int m = 0; m < 2; ++m)
#pragma unroll
    for (int n = 0; n < 2; ++n) {
      const int col = o0 + wc * 32 + n * 16 + (lane & 15);
#pragma unroll
      for (int r = 0; r < 4; ++r) {
        const int row = wr * 32 + m * 16 + (lane >> 4) * 4 + r;
        outp[(size_t)row * NO + col] = acc[m][n][r];
      }
    }
}

// =============== K12: attn (0..127) | gemmA (128..383) | UVW (384..391) ===============
__global__ __launch_bounds__(512) void k12_fused(
    const float* __restrict__ x, const float* __restrict__ gt,
    const float* __restrict__ wt, const float* __restrict__ mt,
    const float* __restrict__ k1w, const float* __restrict__ embk,
    const float* __restrict__ embb, const float* __restrict__ ekd,
    const float* __restrict__ k3w, const float* __restrict__ ng,
    const float* __restrict__ nbv, float* __restrict__ Tfull,
    float* __restrict__ pA, float* __restrict__ U, float* __restrict__ V,
    float* __restrict__ Wc) {
  __shared__ __align__(16) char smem[49152];
  const int bid = blockIdx.x;
  const int t = threadIdx.x;
  const int wv = t >> 6;

  if (bid < NB) {
    // ---- attention: T_b via tilted moments + order-5 Taylor ----
    float* xsh = (float*)smem;
    float(*red)[8] = (float(*)[8])(smem + 4096);
    float* bc = (float*)(smem + 4096 + 7 * 8 * 4);
    *(float2*)&xsh[t * 2] = *(const float2*)&x[bid * ND + t * 2];
    float s1, s3;
    {
      const float kk = embk[NO + t];
      s1 = embk[t] * kk;
      s3 = kk * embb[t];
    }
#pragma unroll
    for (int off = 32; off; off >>= 1) {
      s1 += __shfl_xor(s1, off);
      s3 += __shfl_xor(s3, off);
    }
    if ((t & 63) == 0) { red[0][wv] = s1; red[1][wv] = s3; }
    __syncthreads();
    if (t < 2) {
      float v = 0.f;
#pragma unroll
      for (int i = 0; i < 8; ++i) v += red[t][i];
      bc[t] = v;
    }
    __syncthreads();
    const float S1 = bc[0], S3 = bc[1];
    const float aL2 = SCALEQK * LOG2E * S3;
    const float dS1 = SCALEQK * S1;
    float mm[7];
#pragma unroll
    for (int k = 0; k < 7; ++k) mm[k] = 0.f;
#pragma unroll
    for (int j = 0; j < 2; ++j) {
      const float xe = xsh[t * 2 + j];
      float p = fast_exp2(aL2 * xe);
      mm[0] += p;
#pragma unroll
      for (int k = 1; k < 7; ++k) { p *= xe; mm[k] += p; }
    }
#pragma unroll
    for (int off = 32; off; off >>= 1)
#pragma unroll
      for (int k = 0; k < 7; ++k) mm[k] += __shfl_xor(mm[k], off);
    if ((t & 63) == 0)
#pragma unroll
      for (int k = 0; k < 7; ++k) red[k][wv] = mm[k];
    __syncthreads();
    if (t < 7) {
      float v = 0.f;
#pragma unroll
      for (int i = 0; i < 8; ++i) v += red[t][i];
      bc[2 + t] = v;
    }
    __syncthreads();
    const float invf[6] = {1.f, 1.f, 0.5f, 1.6666667e-1f, 4.1666668e-2f, 8.3333333e-3f};
    float cn[6], cd[6];
#pragma unroll
    for (int k = 0; k < 6; ++k) {
      cn[k] = bc[3 + k] * invf[k];
      cd[k] = bc[2 + k] * invf[k];
    }
    float Ta = 0.f;
#pragma unroll
    for (int j = 0; j < 2; ++j) {
      const int d = t * 2 + j;
      const float del = dS1 * xsh[d];
      float num = cn[5], den = cd[5];
#pragma unroll
      for (int k = 4; k >= 0; --k) {
        num = fmaf(num, del, cn[k]);
        den = fmaf(den, del, cd[k]);
      }
      Ta = fmaf(ekd[d], num / den, Ta);
    }
#pragma unroll
    for (int off = 32; off; off >>= 1) Ta += __shfl_xor(Ta, off);
    __syncthreads();
    if ((t & 63) == 0) red[0][wv] = Ta;
    __syncthreads();
    if (t == 0) {
      float v = 0.f;
#pragma unroll
      for (int i = 0; i < 8; ++i) v += red[0][i];
      Tfull[bid] = v;
    }
    return;
  }
  if (bid < 384) {
    // ---- gemmA: g x ksplit8 x otile8, tile 128x64, K-span 128 ----
    const int b2 = bid - NB;
    const int g = b2 >> 6, ks = (b2 >> 3) & 7, ot = b2 & 7;
    float* outp = pA + (size_t)(g * 8 + ks) * (NB * NO);
    if (g == 0)
      gemmA_tile<1, 0>(x, k1w, k1w, outp, ot * 64, ks * 128, smem);
    else if (g == 1)
      gemmA_tile<1, 0>(x, gt, gt, outp, ot * 64, ks * 128, smem);
    else if (g == 2)
      gemmA_tile<1, 1>(x, wt, mt, outp, ot * 64, ks * 128, smem);
    else
      gemmA_tile<2, 1>(x, wt, mt, outp, ot * 64, ks * 128, smem);
    return;
  }
  // ---- UVW: U=u@K33, V=v@K33, Wc=nb@K33; u=(vk-mvk)*ng, v=(vb-mvb)*ng ----
  {
    float(*lds)[64][3] = (float(*)[64][3])smem;
    __shared__ float mred[2][8];
    __shared__ float mbc[2];
    float svk = embk[2 * NO + t], svb = embb[2 * NO + t];
#pragma unroll
    for (int off = 32; off; off >>= 1) {
      svk += __shfl_xor(svk, off);
      svb += __shfl_xor(svb, off);
    }
    if ((t & 63) == 0) { mred[0][wv] = svk; mred[1][wv] = svb; }
    __syncthreads();
    if (t < 2) {
      float s = 0.f;
#pragma unroll
      for (int i = 0; i < 8; ++i) s += mred[t][i];
      mbc[t] = s * (1.f / (float)NO);
    }
    __syncthreads();
    const float mvk = mbc[0], mvb = mbc[1];
    const int jbase = (bid - 384) * 64;
    const int j = jbase + (t & 63);
    const int oc = t >> 6;
    float au = 0.f, av = 0.f, aw = 0.f;
#pragma unroll 4
    for (int oo = 0; oo < 64; ++oo) {
      const int o = oc * 64 + oo;
      const float kj = k3w[(size_t)(2 * NO + o) * NO + j];
      const float g = ng[o];
      au = fmaf((embk[2 * NO + o] - mvk) * g, kj, au);
      av = fmaf((embb[2 * NO + o] - mvb) * g, kj, av);
      aw = fmaf(nbv[o], kj, aw);
    }
    lds[oc][t & 63][0] = au;
    lds[oc][t & 63][1] = av;
    lds[oc][t & 63][2] = aw;
    __syncthreads();
    if (t < 64) {
      float su = 0.f, sv = 0.f, sw = 0.f;
#pragma unroll
      for (int cch = 0; cch < 8; ++cch) {
        su += lds[cch][t][0];
        sv += lds[cch][t][1];
        sw += lds[cch][t][2];
      }
      U[jbase + t] = su;
      V[jbase + t] = sv;
      Wc[jbase + t] = sw;
    }
  }
}

// =============== K3: combineA -> featP [128][1024] packed (c1 | c3) ===============
__global__ __launch_bounds__(512) void k3_combineA(
    const float* __restrict__ pA, const float* __restrict__ b1,
    u32* __restrict__ featP) {
  const int b = blockIdx.x, t = threadIdx.x;
  const size_t off = (size_t)b * NO + t;
  float d1 = 0.f, d2 = 0.f, d3 = 0.f, d4 = 0.f;
#pragma unroll
  for (int s = 0; s < 8; ++s) {
    d1 += pA[(size_t)(0 * 8 + s) * (NB * NO) + off];
    d2 += pA[(size_t)(1 * 8 + s) * (NB * NO) + off];
    d3 += pA[(size_t)(2 * 8 + s) * (NB * NO) + off];
    d4 += pA[(size_t)(3 * 8 + s) * (NB * NO) + off];
  }
  const float c1v = d1 + b1[t];
  const float gg = sig_fast(d2);
  const float sh = sinh_fast(d4);
  const float c3v = fmaf(gg, d3 - sh, sh);
  u16 h, l;
  bf16_split(c1v, h, l);
  featP[(size_t)b * ND + t] = ((u32)h << 16) | l;
  bf16_split(c3v, h, l);
  featP[(size_t)b * ND + NO + t] = ((u32)h << 16) | l;
}

// =============== K4: gemmB full-K, 32 blocks (4 rowgrp x 8 otile), tile 32x64, BK=128 ===============
// Epilogue fuses bias3 + rank-2 c4 contribution: out = acc + b3 + aS*U + cS*V + Wc.
__global__ __launch_bounds__(512) void k4_gemmB(
    const u32* __restrict__ featP, const float* __restrict__ k3w,
    const float* __restrict__ embk, const float* __restrict__ embb,
    const float* __restrict__ ekd, const float* __restrict__ Tfull,
    const float* __restrict__ U, const float* __restrict__ V,
    const float* __restrict__ Wc, const float* __restrict__ b3,
    float* __restrict__ out) {
  __shared__ __align__(16) char smem[49152];
  u16* AshH = (u16*)smem;                // [32][128] bf16 swizzled, 8 KB
  u16* AshL = (u16*)(smem + 8192);
  u16* BshH = (u16*)(smem + 16384);      // [64 col][128 k] swizzled, 16 KB
  u16* BshL = (u16*)(smem + 32768);
  __shared__ float red6[6][8];
  __shared__ float bc6[6];
  __shared__ float aSl[32];
  __shared__ float cSl[32];

  const int t = threadIdx.x;
  const int wv = t >> 6;
  const int lane = t & 63;
  const int wr = wv & 1, wc2 = wv >> 1;
  const int rg = blockIdx.x >> 3, ot = blockIdx.x & 7;
  const int r0 = rg * 32, o0 = ot * 64;

  // ---- prologue: moments + per-row layernorm scalars ----
  {
    const float vk = embk[2 * NO + t], vb = embb[2 * NO + t];
    float svk = vk, svb = vb, svk2 = vk * vk, svkvb = vk * vb, svb2 = vb * vb;
    float se = ekd[t] + ekd[t + 512];
#pragma unroll
    for (int off = 32; off; off >>= 1) {
      svk += __shfl_xor(svk, off); svb += __shfl_xor(svb, off);
      svk2 += __shfl_xor(svk2, off); svkvb += __shfl_xor(svkvb, off);
      svb2 += __shfl_xor(svb2, off); se += __shfl_xor(se, off);
    }
    if ((t & 63) == 0) {
      red6[0][wv] = svk; red6[1][wv] = svb; red6[2][wv] = svk2;
      red6[3][wv] = svkvb; red6[4][wv] = svb2; red6[5][wv] = se;
    }
    __syncthreads();
    if (t < 6) {
      float s = 0.f;
#pragma unroll
      for (int i = 0; i < 8; ++i) s += red6[t][i];
      bc6[t] = s;
    }
    __syncthreads();
    const float inv_o = 1.f / (float)NO;
    const float mvk = bc6[0] * inv_o, mvb = bc6[1] * inv_o;
    const float Mvk2 = bc6[2] * inv_o - mvk * mvk;
    const float Mvkvb = bc6[3] * inv_o - mvk * mvb;
    const float Mvb2 = bc6[4] * inv_o - mvb * mvb;
    const float E = bc6[5];
    if (t < 32) {
      const float T = Tfull[r0 + t];
      const float var = T * T * Mvk2 + 2.f * T * E * Mvkvb + E * E * Mvb2;
      const float rs = rsqrtf(var + EPSV);
      aSl[t] = T * rs;
      cSl[t] = E * rs;
    }
  }

  const f32x4 vz = {0.f, 0.f, 0.f, 0.f};
  f32x4 acc = vz;

  for (int c = 0; c < 8; ++c) {
    const int kc = c * 128;
    __syncthreads();
    // ---- stage A: featP rows r0..r0+31, k kc..kc+127 (packed u32) ----
    {
      const int row = t >> 4;
      const int j0 = (t & 15) * 8;
      const uint4 v0 = *(const uint4*)(featP + (size_t)(r0 + row) * ND + kc + j0);
      const uint4 v1 = *(const uint4*)(featP + (size_t)(r0 + row) * ND + kc + j0 + 4);
      const uint4 hv = make_uint4(
          (v0.x >> 16) | (v0.y & 0xFFFF0000u), (v0.z >> 16) | (v0.w & 0xFFFF0000u),
          (v1.x >> 16) | (v1.y & 0xFFFF0000u), (v1.z >> 16) | (v1.w & 0xFFFF0000u));
      const uint4 lv = make_uint4(
          (v0.x & 0xFFFFu) | (v0.y << 16), (v0.z & 0xFFFFu) | (v0.w << 16),
          (v1.x & 0xFFFFu) | (v1.y << 16), (v1.z & 0xFFFFu) | (v1.w << 16));
      const int byte = (row * 256 + j0 * 2) ^ ((row & 7) << 4);
      *(uint4*)((char*)AshH + byte) = hv;
      *(uint4*)((char*)AshL + byte) = lv;
    }
    // ---- stage B: k3 rows kc..kc+127, cols o0..o0+63; 2 passes ----
#pragma unroll
    for (int pass = 0; pass < 2; ++pass) {
      const int s = t + pass * 512;
      const int kp = s >> 4, og = s & 15;
      const int gk = kc + kp * 2, go = o0 + og * 4;
      const float4 w0 = *(const float4*)&k3w[(size_t)gk * NO + go];
      const float4 w1 = *(const float4*)&k3w[(size_t)(gk + 1) * NO + go];
      const float e0v[4] = {w0.x, w0.y, w0.z, w0.w};
      const float e1v[4] = {w1.x, w1.y, w1.z, w1.w};
#pragma unroll
      for (int j = 0; j < 4; ++j) {
        u16 h0, l0, h1, l1;
        bf16_split(e0v[j], h0, l0);
        bf16_split(e1v[j], h1, l1);
        const int col = og * 4 + j;
        const int byte = (col * 256 + kp * 4) ^ ((col & 7) << 4);
        *(u32*)((char*)BshH + byte) = (u32)h0 | ((u32)h1 << 16);
        *(u32*)((char*)BshL + byte) = (u32)l0 | ((u32)l1 << 16);
      }
    }
    __syncthreads();
    // ---- compute: 4 k-steps of 32 ----
#pragma unroll
    for (int ks2 = 0; ks2 < 4; ++ks2) {
      const int kb = ks2 * 64 + (lane >> 4) * 16;
      const int row = wr * 16 + (lane & 15);
      const int abyte = (row * 256 + kb) ^ ((row & 7) << 4);
      const bf16x8 a_h = *(const bf16x8*)((const char*)AshH + abyte);
      const bf16x8 a_l = *(const bf16x8*)((const char*)AshL + abyte);
      const int col = wc2 * 16 + (lane & 15);
      const int bbyte = (col * 256 + kb) ^ ((col & 7) << 4);
      const bf16x8 b_h = *(const bf16x8*)((const char*)BshH + bbyte);
      const bf16x8 b_l = *(const bf16x8*)((const char*)BshL + bbyte);
      acc = __builtin_amdgcn_mfma_f32_16x16x32_bf16(a_h, b_h, acc, 0, 0, 0);
      acc = __builtin_amdgcn_mfma_f32_16x16x32_bf16(a_h, b_l, acc, 0, 0, 0);
      acc = __builtin_amdgcn_mfma_f32_16x16x32_bf16(a_l, b_h, acc, 0, 0, 0);
    }
  }
  // ---- epilogue: + bias3 + rank-2 c4 ----
  {
    const int col = o0 + wc2 * 16 + (lane & 15);
    const float uc = U[col], vc = V[col];
    const float base = b3[col] + Wc[col];
#pragma unroll
    for (int r = 0; r < 4; ++r) {
      const int rl = wr * 16 + (lane >> 4) * 4 + r;
      out[(size_t)(r0 + rl) * NO + col] =
          acc[r] + fmaf(aSl[rl], uc, fmaf(cSl[rl], vc, base));
    }
  }
}

extern "C" void kernel_launch(void* const* d_in, const int* in_sizes, int n_in,
                              void* d_out, int out_size, void* d_ws, size_t ws_size,
                              hipStream_t stream) {
  const float* x    = (const float*)d_in[0];
  const float* gt   = (const float*)d_in[1];
  const float* wt   = (const float*)d_in[2];
  const float* mt   = (const float*)d_in[3];
  const float* k1   = (const float*)d_in[4];
  const float* b1   = (const float*)d_in[5];
  const float* k3   = (const float*)d_in[6];
  const float* b3   = (const float*)d_in[7];
  const float* embk = (const float*)d_in[8];
  const float* embb = (const float*)d_in[9];
  const float* ekd  = (const float*)d_in[10];
  const float* ng   = (const float*)d_in[11];
  const float* nb   = (const float*)d_in[12];

  char* wsb = (char*)d_ws;
  float* Tfull = (float*)wsb;                        // 512 B
  float* U  = (float*)(wsb + 4096);                  // 2 KB each
  float* V  = (float*)(wsb + 8192);
  float* Wc = (float*)(wsb + 12288);
  float* pA = (float*)(wsb + (1u << 20));            // 32*128*512*4 = 8 MB
  u32* featP = (u32*)(wsb + (10u << 20));            // 512 KB
  float* out = (float*)d_out;

  hipLaunchKernelGGL(k12_fused, dim3(392), dim3(512), 0, stream,
                     x, gt, wt, mt, k1, embk, embb, ekd, k3, ng, nb,
                     Tfull, pA, U, V, Wc);
  hipLaunchKernelGGL(k3_combineA, dim3(128), dim3(512), 0, stream,
                     pA, b1, featP);
  hipLaunchKernelGGL(k4_gemmB, dim3(32), dim3(512), 0, stream,
                     featP, k3, embk, embb, ekd, Tfull, U, V, Wc, b3, out);
}

// Round 12
// 26.623 us; speedup vs baseline: 1.5438x; 1.5438x over previous
//
#include <hip/hip_runtime.h>
#include <hip/hip_bf16.h>
#include <math.h>

typedef unsigned short u16;
typedef unsigned int u32;
typedef __attribute__((ext_vector_type(8))) short bf16x8;
typedef __attribute__((ext_vector_type(4))) float f32x4;

#define NB 128
#define ND 1024
#define NO 512
#define EPSV 1e-5f
#define SCALEQK 0.04419417382415922f   // 1/sqrt(512)
#define LOG2E 1.4426950408889634f

static __device__ __forceinline__ float fast_exp2(float v) {
#if __has_builtin(__builtin_amdgcn_exp2f)
  return __builtin_amdgcn_exp2f(v);
#else
  return exp2f(v);
#endif
}
static __device__ __forceinline__ float fast_rcp(float v) {
#if __has_builtin(__builtin_amdgcn_rcpf)
  return __builtin_amdgcn_rcpf(v);
#else
  return 1.f / v;
#endif
}
static __device__ __forceinline__ u16 bf16_rtn(float f) {
  unsigned u = __float_as_uint(f);
  return (u16)((u + 0x7FFFu + ((u >> 16) & 1u)) >> 16);
}
static __device__ __forceinline__ float asinh_fast(float x) {
  const float ax = fabsf(x);
  const float s = sqrtf(fmaf(ax, ax, 1.f));
  return copysignf(__logf(ax + s), x);
}
static __device__ __forceinline__ float tanh_fast(float x) {
  return 1.f - 2.f * fast_rcp(fast_exp2(x * (2.f * LOG2E)) + 1.f);
}
static __device__ __forceinline__ float sig_fast(float x) {
  return fast_rcp(1.f + fast_exp2(-x * LOG2E));
}
static __device__ __forceinline__ float sinh_fast(float x) {
  const float z = fast_exp2(x * LOG2E);
  return 0.5f * (z - fast_rcp(z));
}

// =============== gemmA tile: 128 rows x 64 cols, single-pass bf16, K-span 256 (2 chunks of 128) ===============
// LDS: A [128][128] bf16 swizzled (32 KB) + B [64 col][128 k] bf16 (16 KB) = 48 KB.
// AMODE 1 = x, 2 = asinh(x). WMODE 0 = plain W0, 1 = tanh(W0)*sigmoid(W1).
template <int AMODE, int WMODE>
static __device__ __forceinline__ void gemmA_tile(
    const float* __restrict__ Xf, const float* __restrict__ W0,
    const float* __restrict__ W1, float* __restrict__ outp,
    int o0, int k0, char* smem) {
  u16* Ash = (u16*)smem;
  u16* Bsh = (u16*)(smem + 32768);
  const int t = threadIdx.x;
  const int lane = t & 63;
  const int wr = (t >> 6) & 3;
  const int wc = t >> 8;
  const f32x4 vz = {0.f, 0.f, 0.f, 0.f};
  f32x4 acc[2][2];
  acc[0][0] = vz; acc[0][1] = vz; acc[1][0] = vz; acc[1][1] = vz;

#pragma unroll
  for (int c = 0; c < 2; ++c) {
    const int kc = k0 + c * 128;
    if (c) __syncthreads();
    // ---- stage A: 8 passes of 16 rows x 128 k ----
    {
      const int rsub = t >> 5, c4 = (t & 31) * 4;
#pragma unroll
      for (int pass = 0; pass < 8; ++pass) {
        const int row = pass * 16 + rsub;
        const float4 v = *(const float4*)(Xf + (size_t)row * ND + kc + c4);
        float e[4] = {v.x, v.y, v.z, v.w};
        if (AMODE == 2) {
#pragma unroll
          for (int i = 0; i < 4; ++i) e[i] = asinh_fast(e[i]);
        }
        u16 h[4];
#pragma unroll
        for (int i = 0; i < 4; ++i) h[i] = bf16_rtn(e[i]);
        const int byte = (row * 256 + c4 * 2) ^ ((row & 7) << 4);
        *(uint2*)((char*)Ash + byte) =
            make_uint2((u32)h[0] | ((u32)h[1] << 16), (u32)h[2] | ((u32)h[3] << 16));
      }
    }
    // ---- stage B: [col][k] transposed; each thread 4 k-rows x 4 cols ----
    {
      const int gkr = t >> 4, og = t & 15;
      const int go = o0 + og * 4;
#pragma unroll
      for (int kk = 0; kk < 4; ++kk) {
        const int gk = kc + gkr * 4 + kk;
        float4 w0 = *(const float4*)&W0[(size_t)gk * NO + go];
        if (WMODE) {
          const float4 m0 = *(const float4*)&W1[(size_t)gk * NO + go];
          w0.x = tanh_fast(w0.x) * sig_fast(m0.x);
          w0.y = tanh_fast(w0.y) * sig_fast(m0.y);
          w0.z = tanh_fast(w0.z) * sig_fast(m0.z);
          w0.w = tanh_fast(w0.w) * sig_fast(m0.w);
        }
        const float e[4] = {w0.x, w0.y, w0.z, w0.w};
#pragma unroll
        for (int j = 0; j < 4; ++j) {
          const int col = og * 4 + j;
          const int byte = (col * 256 + (gkr * 4 + kk) * 2) ^ ((col & 7) << 4);
          *(u16*)((char*)Bsh + byte) = bf16_rtn(e[j]);
        }
      }
    }
    __syncthreads();
    // ---- compute: 4 k-steps of 32 ----
#pragma unroll
    for (int ks2 = 0; ks2 < 4; ++ks2) {
      const int kbyte = ks2 * 64 + (lane >> 4) * 16;
      bf16x8 a[2], b[2];
#pragma unroll
      for (int m = 0; m < 2; ++m) {
        const int row = wr * 32 + m * 16 + (lane & 15);
        a[m] = *(const bf16x8*)((const char*)Ash + ((row * 256 + kbyte) ^ ((row & 7) << 4)));
      }
#pragma unroll
      for (int n = 0; n < 2; ++n) {
        const int col = wc * 32 + n * 16 + (lane & 15);
        b[n] = *(const bf16x8*)((const char*)Bsh + ((col * 256 + kbyte) ^ ((col & 7) << 4)));
      }
#pragma unroll
      for (int m = 0; m < 2; ++m)
#pragma unroll
        for (int n = 0; n < 2; ++n)
          acc[m][n] = __builtin_amdgcn_mfma_f32_16x16x32_bf16(a[m], b[n], acc[m][n], 0, 0, 0);
    }
  }
  // ---- epilogue: C/D layout col=lane&15, row=(lane>>4)*4+reg ----
#pragma unroll
  for (int m = 0; m < 2; ++m)
#pragma unroll
    for (int n = 0; n < 2; ++n) {
      const int col = o0 + wc * 32 + n * 16 + (lane & 15);
#pragma unroll
      for (int r = 0; r < 4; ++r) {
        const int row = wr * 32 + m * 16 + (lane >> 4) * 4 + r;
        outp[(size_t)row * NO + col] = acc[m][n][r];
      }
    }
}

// =============== K1: attn (0..127) | gemmA (128..255: g4 x ks4 x ot8) | UVW (256..263) ===============
__global__ __launch_bounds__(512) void k1_fused(
    const float* __restrict__ x, const float* __restrict__ gt,
    const float* __restrict__ wt, const float* __restrict__ mt,
    const float* __restrict__ k1w, const float* __restrict__ embk,
    const float* __restrict__ embb, const float* __restrict__ ekd,
    const float* __restrict__ k3w, const float* __restrict__ ng,
    const float* __restrict__ nbv, float* __restrict__ Tfull,
    float* __restrict__ pA, float* __restrict__ U, float* __restrict__ V,
    float* __restrict__ Wc) {
  __shared__ __align__(16) char smem[49152];
  const int bid = blockIdx.x;
  const int t = threadIdx.x;
  const int wv = t >> 6;

  if (bid < NB) {
    // ---- attention: T_b via tilted moments + order-5 Taylor ----
    float* xsh = (float*)smem;
    float(*red)[8] = (float(*)[8])(smem + 4096);
    float* bc = (float*)(smem + 4096 + 7 * 8 * 4);
    *(float2*)&xsh[t * 2] = *(const float2*)&x[bid * ND + t * 2];
    float s1, s3;
    {
      const float kk = embk[NO + t];
      s1 = embk[t] * kk;
      s3 = kk * embb[t];
    }
#pragma unroll
    for (int off = 32; off; off >>= 1) {
      s1 += __shfl_xor(s1, off);
      s3 += __shfl_xor(s3, off);
    }
    if ((t & 63) == 0) { red[0][wv] = s1; red[1][wv] = s3; }
    __syncthreads();
    if (t < 2) {
      float v = 0.f;
#pragma unroll
      for (int i = 0; i < 8; ++i) v += red[t][i];
      bc[t] = v;
    }
    __syncthreads();
    const float S1 = bc[0], S3 = bc[1];
    const float aL2 = SCALEQK * LOG2E * S3;
    const float dS1 = SCALEQK * S1;
    float mm[7];
#pragma unroll
    for (int k = 0; k < 7; ++k) mm[k] = 0.f;
#pragma unroll
    for (int j = 0; j < 2; ++j) {
      const float xe = xsh[t * 2 + j];
      float p = fast_exp2(aL2 * xe);
      mm[0] += p;
#pragma unroll
      for (int k = 1; k < 7; ++k) { p *= xe; mm[k] += p; }
    }
#pragma unroll
    for (int off = 32; off; off >>= 1)
#pragma unroll
      for (int k = 0; k < 7; ++k) mm[k] += __shfl_xor(mm[k], off);
    if ((t & 63) == 0)
#pragma unroll
      for (int k = 0; k < 7; ++k) red[k][wv] = mm[k];
    __syncthreads();
    if (t < 7) {
      float v = 0.f;
#pragma unroll
      for (int i = 0; i < 8; ++i) v += red[t][i];
      bc[2 + t] = v;
    }
    __syncthreads();
    const float invf[6] = {1.f, 1.f, 0.5f, 1.6666667e-1f, 4.1666668e-2f, 8.3333333e-3f};
    float cn[6], cd[6];
#pragma unroll
    for (int k = 0; k < 6; ++k) {
      cn[k] = bc[3 + k] * invf[k];
      cd[k] = bc[2 + k] * invf[k];
    }
    float Ta = 0.f;
#pragma unroll
    for (int j = 0; j < 2; ++j) {
      const int d = t * 2 + j;
      const float del = dS1 * xsh[d];
      float num = cn[5], den = cd[5];
#pragma unroll
      for (int k = 4; k >= 0; --k) {
        num = fmaf(num, del, cn[k]);
        den = fmaf(den, del, cd[k]);
      }
      Ta = fmaf(ekd[d], num / den, Ta);
    }
#pragma unroll
    for (int off = 32; off; off >>= 1) Ta += __shfl_xor(Ta, off);
    __syncthreads();
    if ((t & 63) == 0) red[0][wv] = Ta;
    __syncthreads();
    if (t == 0) {
      float v = 0.f;
#pragma unroll
      for (int i = 0; i < 8; ++i) v += red[0][i];
      Tfull[bid] = v;
    }
    return;
  }
  if (bid < 256) {
    // ---- gemmA ----
    const int b2 = bid - NB;
    const int g = b2 >> 5, ks = (b2 >> 3) & 3, ot = b2 & 7;
    float* outp = pA + (size_t)(g * 4 + ks) * (NB * NO);
    if (g == 0)
      gemmA_tile<1, 0>(x, k1w, k1w, outp, ot * 64, ks * 256, smem);
    else if (g == 1)
      gemmA_tile<1, 0>(x, gt, gt, outp, ot * 64, ks * 256, smem);
    else if (g == 2)
      gemmA_tile<1, 1>(x, wt, mt, outp, ot * 64, ks * 256, smem);
    else
      gemmA_tile<2, 1>(x, wt, mt, outp, ot * 64, ks * 256, smem);
    return;
  }
  // ---- UVW: U=u@K33, V=v@K33, Wc=nb@K33; u=(vk-mvk)*ng, v=(vb-mvb)*ng ----
  {
    float(*lds)[64][3] = (float(*)[64][3])smem;
    __shared__ float mred[2][8];
    __shared__ float mbc[2];
    float svk = embk[2 * NO + t], svb = embb[2 * NO + t];
#pragma unroll
    for (int off = 32; off; off >>= 1) {
      svk += __shfl_xor(svk, off);
      svb += __shfl_xor(svb, off);
    }
    if ((t & 63) == 0) { mred[0][wv] = svk; mred[1][wv] = svb; }
    __syncthreads();
    if (t < 2) {
      float s = 0.f;
#pragma unroll
      for (int i = 0; i < 8; ++i) s += mred[t][i];
      mbc[t] = s * (1.f / (float)NO);
    }
    __syncthreads();
    const float mvk = mbc[0], mvb = mbc[1];
    const int jbase = (bid - 256) * 64;
    const int j = jbase + (t & 63);
    const int oc = t >> 6;
    float au = 0.f, av = 0.f, aw = 0.f;
#pragma unroll 4
    for (int oo = 0; oo < 64; ++oo) {
      const int o = oc * 64 + oo;
      const float kj = k3w[(size_t)(2 * NO + o) * NO + j];
      const float g = ng[o];
      au = fmaf((embk[2 * NO + o] - mvk) * g, kj, au);
      av = fmaf((embb[2 * NO + o] - mvb) * g, kj, av);
      aw = fmaf(nbv[o], kj, aw);
    }
    lds[oc][t & 63][0] = au;
    lds[oc][t & 63][1] = av;
    lds[oc][t & 63][2] = aw;
    __syncthreads();
    if (t < 64) {
      float su = 0.f, sv = 0.f, sw = 0.f;
#pragma unroll
      for (int cch = 0; cch < 8; ++cch) {
        su += lds[cch][t][0];
        sv += lds[cch][t][1];
        sw += lds[cch][t][2];
      }
      U[jbase + t] = su;
      V[jbase + t] = sv;
      Wc[jbase + t] = sw;
    }
  }
}

// =============== K2: combineA -> featB (bf16) + out init (b3 + rank-2 c4) ===============
__global__ __launch_bounds__(512) void k2_combineA(
    const float* __restrict__ pA, const float* __restrict__ b1,
    const float* __restrict__ embk, const float* __restrict__ embb,
    const float* __restrict__ ekd, const float* __restrict__ Tfull,
    const float* __restrict__ U, const float* __restrict__ V,
    const float* __restrict__ Wc, const float* __restrict__ b3,
    u16* __restrict__ featB, float* __restrict__ out) {
  __shared__ float red6[6][8];
  __shared__ float bc6[6];
  const int b = blockIdx.x, t = threadIdx.x;
  const int wv = t >> 6;
  // moments over o + E
  {
    const float vk = embk[2 * NO + t], vb = embb[2 * NO + t];
    float svk = vk, svb = vb, svk2 = vk * vk, svkvb = vk * vb, svb2 = vb * vb;
    float se = ekd[t] + ekd[t + 512];
#pragma unroll
    for (int off = 32; off; off >>= 1) {
      svk += __shfl_xor(svk, off); svb += __shfl_xor(svb, off);
      svk2 += __shfl_xor(svk2, off); svkvb += __shfl_xor(svkvb, off);
      svb2 += __shfl_xor(svb2, off); se += __shfl_xor(se, off);
    }
    if ((t & 63) == 0) {
      red6[0][wv] = svk; red6[1][wv] = svb; red6[2][wv] = svk2;
      red6[3][wv] = svkvb; red6[4][wv] = svb2; red6[5][wv] = se;
    }
    __syncthreads();
    if (t < 6) {
      float s = 0.f;
#pragma unroll
      for (int i = 0; i < 8; ++i) s += red6[t][i];
      bc6[t] = s;
    }
    __syncthreads();
  }
  const float inv_o = 1.f / (float)NO;
  const float mvk = bc6[0] * inv_o, mvb = bc6[1] * inv_o;
  const float Mvk2 = bc6[2] * inv_o - mvk * mvk;
  const float Mvkvb = bc6[3] * inv_o - mvk * mvb;
  const float Mvb2 = bc6[4] * inv_o - mvb * mvb;
  const float E = bc6[5];
  const float T = Tfull[b];
  const float var = T * T * Mvk2 + 2.f * T * E * Mvkvb + E * E * Mvb2;
  const float rs = rsqrtf(var + EPSV);
  const float aS = T * rs, cS = E * rs;

  const size_t off = (size_t)b * NO + t;
  float d1 = 0.f, d2 = 0.f, d3 = 0.f, d4 = 0.f;
#pragma unroll
  for (int s = 0; s < 4; ++s) {
    d1 += pA[(size_t)(0 * 4 + s) * (NB * NO) + off];
    d2 += pA[(size_t)(1 * 4 + s) * (NB * NO) + off];
    d3 += pA[(size_t)(2 * 4 + s) * (NB * NO) + off];
    d4 += pA[(size_t)(3 * 4 + s) * (NB * NO) + off];
  }
  const float c1v = d1 + b1[t];
  const float gg = sig_fast(d2);
  const float sh = sinh_fast(d4);
  const float c3v = fmaf(gg, d3 - sh, sh);
  featB[(size_t)b * ND + t] = bf16_rtn(c1v);
  featB[(size_t)b * ND + NO + t] = bf16_rtn(c3v);
  out[off] = fmaf(aS, U[t], fmaf(cS, V[t], b3[t] + Wc[t]));
}

// =============== K3: gemmB 128 blocks (2 rh x 8 ks x 8 ot), tile 64x64, K=128, atomic out ===============
__global__ __launch_bounds__(512) void k3_gemmB(
    const u16* __restrict__ featB, const float* __restrict__ k3w,
    float* __restrict__ out) {
  __shared__ __align__(16) char smem[32768];
  u16* Ash = (u16*)smem;                 // [64][128] bf16 swizzled, 16 KB
  u16* Bsh = (u16*)(smem + 16384);       // [64 col][128 k], 16 KB
  const int t = threadIdx.x;
  const int lane = t & 63;
  const int wr = (t >> 6) & 3;
  const int wc = t >> 8;
  const int rh = blockIdx.x >> 6, ks = (blockIdx.x >> 3) & 7, ot = blockIdx.x & 7;
  const int r0 = rh * 64, k0 = ks * 128, o0 = ot * 64;

  // ---- stage A: featB rows r0..r0+63, k k0..k0+127 (plain bf16 copy) ----
#pragma unroll
  for (int p2 = 0; p2 < 2; ++p2) {
    const int s = t + p2 * 512;
    const int row = s >> 4, j8 = (s & 15) * 8;
    const uint4 v = *(const uint4*)(featB + (size_t)(r0 + row) * ND + k0 + j8);
    const int byte = (row * 256 + j8 * 2) ^ ((row & 7) << 4);
    *(uint4*)((char*)Ash + byte) = v;
  }
  // ---- stage B: k3 rows k0..k0+127, cols o0..o0+63 ----
  {
    const int gkr = t >> 4, og = t & 15;
    const int go = o0 + og * 4;
#pragma unroll
    for (int kk = 0; kk < 4; ++kk) {
      const int gk = k0 + gkr * 4 + kk;
      const float4 w0 = *(const float4*)&k3w[(size_t)gk * NO + go];
      const float e[4] = {w0.x, w0.y, w0.z, w0.w};
#pragma unroll
      for (int j = 0; j < 4; ++j) {
        const int col = og * 4 + j;
        const int byte = (col * 256 + (gkr * 4 + kk) * 2) ^ ((col & 7) << 4);
        *(u16*)((char*)Bsh + byte) = bf16_rtn(e[j]);
      }
    }
  }
  __syncthreads();
  // ---- compute: 4 k-steps of 32; tile 64x64 with 8 waves (wr4 x wc2), acc[1][2] ----
  const f32x4 vz = {0.f, 0.f, 0.f, 0.f};
  f32x4 acc[2];
  acc[0] = vz; acc[1] = vz;
#pragma unroll
  for (int ks2 = 0; ks2 < 4; ++ks2) {
    const int kbyte = ks2 * 64 + (lane >> 4) * 16;
    const int row = wr * 16 + (lane & 15);
    const bf16x8 a = *(const bf16x8*)((const char*)Ash + ((row * 256 + kbyte) ^ ((row & 7) << 4)));
#pragma unroll
    for (int n = 0; n < 2; ++n) {
      const int col = wc * 32 + n * 16 + (lane & 15);
      const bf16x8 b = *(const bf16x8*)((const char*)Bsh + ((col * 256 + kbyte) ^ ((col & 7) << 4)));
      acc[n] = __builtin_amdgcn_mfma_f32_16x16x32_bf16(a, b, acc[n], 0, 0, 0);
    }
  }
  // ---- epilogue: atomicAdd into pre-initialized out ----
#pragma unroll
  for (int n = 0; n < 2; ++n) {
    const int col = o0 + wc * 32 + n * 16 + (lane & 15);
#pragma unroll
    for (int r = 0; r < 4; ++r) {
      const int row = r0 + wr * 16 + (lane >> 4) * 4 + r;
      atomicAdd(&out[(size_t)row * NO + col], acc[n][r]);
    }
  }
}

extern "C" void kernel_launch(void* const* d_in, const int* in_sizes, int n_in,
                              void* d_out, int out_size, void* d_ws, size_t ws_size,
                              hipStream_t stream) {
  const float* x    = (const float*)d_in[0];
  const float* gt   = (const float*)d_in[1];
  const float* wt   = (const float*)d_in[2];
  const float* mt   = (const float*)d_in[3];
  const float* k1   = (const float*)d_in[4];
  const float* b1   = (const float*)d_in[5];
  const float* k3   = (const float*)d_in[6];
  const float* b3   = (const float*)d_in[7];
  const float* embk = (const float*)d_in[8];
  const float* embb = (const float*)d_in[9];
  const float* ekd  = (const float*)d_in[10];
  const float* ng   = (const float*)d_in[11];
  const float* nb   = (const float*)d_in[12];

  char* wsb = (char*)d_ws;
  float* Tfull = (float*)wsb;                        // 512 B
  float* U  = (float*)(wsb + 4096);                  // 2 KB each
  float* V  = (float*)(wsb + 8192);
  float* Wc = (float*)(wsb + 12288);
  float* pA = (float*)(wsb + (1u << 20));            // 16*128*512*4 = 4 MB
  u16* featB = (u16*)(wsb + (6u << 20));             // 128*1024*2 = 256 KB
  float* out = (float*)d_out;

  hipLaunchKernelGGL(k1_fused, dim3(264), dim3(512), 0, stream,
                     x, gt, wt, mt, k1, embk, embb, ekd, k3, ng, nb,
                     Tfull, pA, U, V, Wc);
  hipLaunchKernelGGL(k2_combineA, dim3(128), dim3(512), 0, stream,
                     pA, b1, embk, embb, ekd, Tfull, U, V, Wc, b3, featB, out);
  hipLaunchKernelGGL(k3_gemmB, dim3(128), dim3(512), 0, stream,
                     featB, k3, out);
}